// Round 13
// baseline (67.226 us; speedup 1.0000x reference)
//
#include <hip/hip_runtime.h>

// Problem constants (match reference)
#define RN      2000
#define NMAT    16            // B(4) * L(4)
#define INV400  0.0025f       // 1/sqrt(E2); E2 = 160000 -> scaled off-diag = 1

// Segmentation: 9 segments x 208 rows + 8 junction blocks x 16 rows = 2000.
#define SEGL    208
#define JW      16
#define PERIOD  224
#define NJUNC   8
#define NCHAIN  16            // 8 fwd (segs 0..7) + 8 bwd (segs 1..8)
#define NGRP    13            // SEGL / 16
#define STRIDE  232           // stream stride (floats): 16B-aligned

// Probe grid: 2 probes/thread -> 32 slots/chunk, 17 chunks x stride 31 + 1
// = 528 probes/matrix. Blocks = 16*17 = 272 (~1 wave/SIMD: no stacking).
#define CSTRIDE 31
#define NCHUNK  17
#define NPT     (NCHUNK*CSTRIDE + 1)   // 528

// Analytic per-l bounds (r10-verified): lo = -60, hi = 1660 + 400*ll1.
#define PLO     (-60.0f)

// nu(T-xI) = sum_s nu(seg_s) + sum_j nu(junction_j)  (Haynsworth; HW-validated
// r5/r9/r10/r12). Division-free scaled polynomial recurrence per segment:
//   w_i = fma((d_i-x)/400, w_{i-1}, -w_{i-2}),  nu = # sign changes,
// (w1,w2) exponent-renormalized every 16 iters. Junction = 16x16 tridiag with
// corner corrections fr = w2f/w1f, br = w2b/w1b (clamped +-1e9: sign-exact,
// and 1e9 * 15.6^15 * 1e9 < f32max kills the inf-inf NaN corner).
//
// r13 change: TWO interleaved probe-chains per thread (ILP fills the FMA
// latency bubbles measured at 48cy/iter in r4) + blocks 544->272 (removes
// the 2.1x block stacking). Total probe work unchanged.
__global__ __launch_bounds__(256)
void eval_eig_fused(const float* __restrict__ ptl, float* __restrict__ out) {
    const int t  = threadIdx.x;
    const int m  = blockIdx.x / NCHUNK;   // matrix index (b*4 + l)
    const int ch = blockIdx.x - m * NCHUNK;
    const int b  = m >> 2;
    const int l  = m & 3;
    const float ll1 = (float)(l * (l + 1));

    __shared__ float st[NCHAIN][STRIDE];  // chain-major scaled-diag streams
    __shared__ float dj[NJUNC][JW];       // scaled junction diagonals
    __shared__ float xw1[NJUNC][32], xw2[NJUNC][32];  // bwd-chain final pairs
    __shared__ int   xct[NCHAIN][32];
    __shared__ int   jct[NJUNC][32];
    __shared__ int   sc[32];

    // ---- (1) scaled diag into LDS: d/400 = 2 + 0.0025*ptl + ll1/(i+1)^2 --
    const float* prow = ptl + b * RN;
    for (int i = t; i < RN; i += 256) {
        float fi = (float)(i + 1);                     // exact for i<2000
        float v  = 2.0f + 0.0025f * prow[i]
                 + ll1 * __builtin_amdgcn_rcpf(fi * fi);
        int q  = i / PERIOD;                           // 0..8
        int rr = i - q * PERIOD;
        if (rr < SEGL) {
            if (q < 8)  st[q][rr] = v;                 // fwd chain q
            if (q >= 1) st[7 + q][SEGL - 1 - rr] = v;  // bwd chain (segs 1..8)
        } else {
            dj[q][rr - SEGL] = v;                      // junction q (q<=7)
        }
    }
    __syncthreads();

    const float lo   = PLO;
    const float hi   = 1660.0f + 400.0f * ll1;
    const float step = (hi - lo) / (float)(NPT + 1);

    // ---- (2) two interleaved 208-iter chains per thread ------------------
    const int   p   = t & 15;                   // probe sub-slot
    const int   c   = t >> 4;                   // chain index
    const int   s0  = p, s1 = p + 16;           // the two slots this thread owns
    const float xa  = lo + step * (float)(ch * CSTRIDE + s0 + 1);
    const float xb  = lo + step * (float)(ch * CSTRIDE + s1 + 1);
    const float xa4 = xa * INV400;
    const float xb4 = xb * INV400;

    const float4* s4 = (const float4*)&st[c][0];

    float w1a = 1.0f, w2a = 0.0f, w1b = 1.0f, w2b = 0.0f;
    unsigned spa = 0u, spb = 0u;
    int ca = 0, cb = 0;
    float4 A = s4[0], B = s4[1], C = s4[2], D = s4[3];

#define SITER2(dv)                                           \
    {                                                        \
        float wA = __builtin_fmaf((dv) - xa4, w1a, -w2a);    \
        float wB = __builtin_fmaf((dv) - xb4, w1b, -w2b);    \
        unsigned sA = __float_as_uint(wA) >> 31;             \
        unsigned sB = __float_as_uint(wB) >> 31;             \
        ca += (int)(sA ^ spa); spa = sA; w2a = w1a; w1a = wA;\
        cb += (int)(sB ^ spb); spb = sB; w2b = w1b; w1b = wB;\
    }

#define RENORM(w1v, w2v)                                            \
    {                                                               \
        unsigned b1 = __float_as_uint(w1v), b2 = __float_as_uint(w2v); \
        unsigned e1 = (b1 >> 23) & 0xFFu, e2 = (b2 >> 23) & 0xFFu;  \
        unsigned em = e1 > e2 ? e1 : e2;                            \
        unsigned sh = em > 127u ? em - 127u : 0u;                   \
        unsigned sb = sh << 23;                                     \
        w1v = __uint_as_float((e1 <= sh) ? (b1 & 0x80000000u) : (b1 - sb)); \
        w2v = __uint_as_float((e2 <= sh) ? (b2 & 0x80000000u) : (b2 - sb)); \
    }

    for (int g = 0; g < NGRP; ++g) {
        float4 An = s4[4 * g + 4];              // prefetch next 16 (g=12 ->
        float4 Bn = s4[4 * g + 5];              // floats 208..223 < 232: in
        float4 Cn = s4[4 * g + 6];              // stream bounds, values unused)
        float4 Dn = s4[4 * g + 7];

        SITER2(A.x) SITER2(A.y) SITER2(A.z) SITER2(A.w)
        SITER2(B.x) SITER2(B.y) SITER2(B.z) SITER2(B.w)
        SITER2(C.x) SITER2(C.y) SITER2(C.z) SITER2(C.w)
        SITER2(D.x) SITER2(D.y) SITER2(D.z) SITER2(D.w)

        RENORM(w1a, w2a)
        RENORM(w1b, w2b)
        A = An; B = Bn; C = Cn; D = Dn;
    }
#undef SITER2

    // ---- (3) exchange, junction polynomial chains, per-probe totals ------
    if (c >= 8) {
        xw1[c - 8][s0] = w1a; xw2[c - 8][s0] = w2a;
        xw1[c - 8][s1] = w1b; xw2[c - 8][s1] = w2b;
    }
    xct[c][s0] = ca;
    xct[c][s1] = cb;
    __syncthreads();

    if (c < NJUNC) {
#define JCHAIN(w1v, w2v, slot)                                      \
        {                                                           \
            float fr = w2v * __builtin_amdgcn_rcpf(w1v);            \
            fr = fminf(fmaxf(fr, -1e9f), 1e9f);                     \
            float bb1 = xw1[c][slot], bb2 = xw2[c][slot];           \
            float br = bb2 * __builtin_amdgcn_rcpf(bb1);            \
            br = fminf(fmaxf(br, -1e9f), 1e9f);                     \
            float xq = (slot == s0) ? xa4 : xb4;                    \
            float u0 = 0.0f, u1 = 1.0f;                             \
            unsigned sj = 0u;                                       \
            int jc = 0;                                             \
            _Pragma("unroll")                                       \
            for (int r = 0; r < JW; ++r) {                          \
                float a = dj[c][r] - xq;                            \
                if (r == 0)      a -= fr;                           \
                if (r == JW - 1) a -= br;                           \
                float u = __builtin_fmaf(a, u1, -u0);               \
                unsigned s_ = __float_as_uint(u) >> 31;             \
                jc += (int)(s_ ^ sj);                               \
                sj = s_;                                            \
                u0 = u1; u1 = u;                                    \
            }                                                       \
            jct[c][slot] = jc;                                      \
        }
        JCHAIN(w1a, w2a, s0)
        JCHAIN(w1b, w2b, s1)
#undef JCHAIN
    }
    __syncthreads();

    if (c == 0) {
        int t0 = xct[15][s0], t1 = xct[15][s1];   // seg 8 via its bwd chain
        #pragma unroll
        for (int cc = 0; cc < 8; ++cc) {
            t0 += xct[cc][s0] + jct[cc][s0];
            t1 += xct[cc][s1] + jct[cc][s1];
        }
        sc[s0] = t0;
        sc[s1] = t1;
    }
    __syncthreads();

    // ---- (4) scatter eigenvalues (bracket-union, verified r3-r12) --------
    if (c == 0) {
        float* o = out + m * RN;
        // slot s0
        {
            const int ccur = sc[s0];
            if (s0 > 0) {
                const int cprev = sc[s0 - 1];
                const float xm = xa - 0.5f * step;
                for (int k = cprev; k < ccur; ++k) o[k] = xm;
            } else if (ch == 0) {
                const float xm = xa - 0.5f * step;   // bracket (lo, x_0]
                for (int k = 0; k < ccur; ++k) o[k] = xm;
            }
        }
        // slot s1 (always has in-block predecessor)
        {
            const int ccur = sc[s1];
            const int cprev = sc[s1 - 1];
            const float xm = xb - 0.5f * step;
            for (int k = cprev; k < ccur; ++k) o[k] = xm;
            if (ch == NCHUNK - 1 && s1 == 31) {      // bracket (x_last, hi]
                const float xm2 = xb + 0.5f * step;
                for (int k = ccur; k < RN; ++k) o[k] = xm2;
            }
        }
    }
}

// ---------------------------------------------------------------------------
extern "C" void kernel_launch(void* const* d_in, const int* in_sizes, int n_in,
                              void* d_out, int out_size, void* d_ws, size_t ws_size,
                              hipStream_t stream) {
    const float* ptl = (const float*)d_in[0];   // (B=4, RN) f32
    float* out = (float*)d_out;                 // (4, 4, RN) f32 ascending

    eval_eig_fused<<<NMAT * NCHUNK, 256, 0, stream>>>(ptl, out);
}

// Round 14
// 61.294 us; speedup vs baseline: 1.0968x; 1.0968x over previous
//
#include <hip/hip_runtime.h>

// Problem constants (match reference)
#define RN      2000
#define NMAT    16            // B(4) * L(4)
#define INV400  0.0025f       // 1/sqrt(E2); E2 = 160000 -> scaled off-diag = 1

// Segmentation: 9 segments x 208 rows + 8 junction blocks x 16 rows = 2000.
#define SEGL    208
#define JW      16
#define PERIOD  224
#define NJUNC   8
#define NCHAIN  16            // 8 fwd (segs 0..7) + 8 bwd (segs 1..8)
#define NGRP    13            // SEGL / 16
#define STRIDE  232           // stream stride (floats): 16B-aligned

// Probe grid: 32 chunks x stride 15 + 1 = 481 probes/matrix.
// r14 change (ONLY vs r12): NCHUNK 34 -> 32 => 512 blocks = EXACTLY 2.0
// blocks/CU. r9-r12's 544 blocks put 3 blocks on 32 CUs (ceil tier); the
// whole dispatch waited on that 1.5x-slower tail: wall = ceil(blocks/256) *
// T_block (model closes r4/r9-r12/r13 within noise). 3 tiers -> 2.
#define CSTRIDE 15
#define NCHUNK  32
#define NPT     (NCHUNK*CSTRIDE + 1)   // 481

// Analytic per-l bounds (r10-verified): lo = -60, hi = 1660 + 400*ll1.
#define PLO     (-60.0f)

// nu(T-xI) = sum_s nu(seg_s) + sum_j nu(junction_j)  (Haynsworth; HW-validated
// r5/r9/r10/r12/r13). Division-free scaled polynomial recurrence per segment:
//   w_i = fma((d_i-x)/400, w_{i-1}, -w_{i-2}),  nu = # sign changes,
// (w1,w2) exponent-renormalized every 16 iters (downscale-only, sign-safe).
// Junction = 16x16 tridiag with corner corrections fr = w2f/w1f, br = w2b/w1b.
__global__ __launch_bounds__(256)
void eval_eig_fused(const float* __restrict__ ptl, float* __restrict__ out) {
    const int t  = threadIdx.x;
    const int m  = blockIdx.x / NCHUNK;   // matrix index (b*4 + l)
    const int ch = blockIdx.x - m * NCHUNK;
    const int b  = m >> 2;
    const int l  = m & 3;
    const float ll1 = (float)(l * (l + 1));

    __shared__ float st[NCHAIN][STRIDE];  // chain-major scaled-diag streams
    __shared__ float dj[NJUNC][JW];       // scaled junction diagonals
    __shared__ float xw1[NJUNC][16], xw2[NJUNC][16];  // bwd-chain final pairs
    __shared__ int   xct[NCHAIN][16];
    __shared__ int   jct[NJUNC][16];
    __shared__ int   sc[16];

    // ---- (1) scaled diag into LDS: d/400 = 2 + 0.0025*ptl + ll1/(i+1)^2 --
    const float* prow = ptl + b * RN;
    for (int i = t; i < RN; i += 256) {
        float fi = (float)(i + 1);                     // exact for i<2000
        float v  = 2.0f + 0.0025f * prow[i]
                 + ll1 * __builtin_amdgcn_rcpf(fi * fi);
        int q  = i / PERIOD;                           // 0..8
        int rr = i - q * PERIOD;
        if (rr < SEGL) {
            if (q < 8)  st[q][rr] = v;                 // fwd chain q
            if (q >= 1) st[7 + q][SEGL - 1 - rr] = v;  // bwd chain (segs 1..8)
        } else {
            dj[q][rr - SEGL] = v;                      // junction q (q<=7)
        }
    }
    __syncthreads();

    const float lo   = PLO;
    const float hi   = 1660.0f + 400.0f * ll1;
    const float step = (hi - lo) / (float)(NPT + 1);

    // ---- (2) one 208-iter chain per thread -------------------------------
    const int   p    = t & 15;                  // probe slot
    const int   c    = t >> 4;                  // chain index
    const int   pg   = ch * CSTRIDE + p;        // global probe 0..480
    const float x    = lo + step * (float)(pg + 1);
    const float x400 = x * INV400;

    const float4* s4 = (const float4*)&st[c][0];

    float w2 = 0.0f, w1 = 1.0f;                 // w_{-1}=0, w_0=1
    unsigned sp = 0u;
    int cnt = 0;
    float4 A = s4[0], B = s4[1], C = s4[2], D = s4[3];

#define SITER(dv)                                            \
    {                                                        \
        float w = __builtin_fmaf((dv) - x400, w1, -w2);      \
        unsigned s_ = __float_as_uint(w) >> 31;              \
        cnt += (int)(s_ ^ sp);                               \
        sp = s_;                                             \
        w2 = w1; w1 = w;                                     \
    }

    for (int g = 0; g < NGRP; ++g) {
        float4 An = s4[4 * g + 4];              // prefetch next 16 (g=12 ->
        float4 Bn = s4[4 * g + 5];              // floats 208..223 < 232: in
        float4 Cn = s4[4 * g + 6];              // stream bounds, values unused)
        float4 Dn = s4[4 * g + 7];

        SITER(A.x) SITER(A.y) SITER(A.z) SITER(A.w)
        SITER(B.x) SITER(B.y) SITER(B.z) SITER(B.w)
        SITER(C.x) SITER(C.y) SITER(C.z) SITER(C.w)
        SITER(D.x) SITER(D.y) SITER(D.z) SITER(D.w)

        {   // renormalize pair: common positive scale 2^-sh, signs preserved
            unsigned b1 = __float_as_uint(w1), b2v = __float_as_uint(w2);
            unsigned e1 = (b1 >> 23) & 0xFFu, e2 = (b2v >> 23) & 0xFFu;
            unsigned em = e1 > e2 ? e1 : e2;
            unsigned sh = em > 127u ? em - 127u : 0u;   // downscale only
            unsigned sb = sh << 23;
            unsigned n1 = (e1 <= sh) ? (b1  & 0x80000000u) : (b1  - sb);
            unsigned n2 = (e2 <= sh) ? (b2v & 0x80000000u) : (b2v - sb);
            w1 = __uint_as_float(n1);
            w2 = __uint_as_float(n2);
        }
        A = An; B = Bn; C = Cn; D = Dn;
    }
#undef SITER

    // ---- (3) exchange, junction polynomial chains, per-probe total -------
    if (c >= 8) { xw1[c - 8][p] = w1; xw2[c - 8][p] = w2; }
    xct[c][p] = cnt;
    __syncthreads();

    if (c < NJUNC) {
        // left = own fwd pair (seg c); right = bwd chain 8+c (seg c+1)
        float fr = w2 * __builtin_amdgcn_rcpf(w1);
        fr = fminf(fmaxf(fr, -1e18f), 1e18f);   // clamp: sign-exact, no inf
        float b1v = xw1[c][p], b2v = xw2[c][p];
        float br = b2v * __builtin_amdgcn_rcpf(b1v);
        br = fminf(fmaxf(br, -1e18f), 1e18f);

        // division-free junction: 16-step polynomial recurrence, corners
        // folded into a_0 and a_15. Growth <= 14.1^15 from 1e18 < f32 max.
        float u0 = 0.0f, u1 = 1.0f;
        unsigned sj = 0u;
        int jc = 0;
        #pragma unroll
        for (int r = 0; r < JW; ++r) {
            float a = dj[c][r] - x400;
            if (r == 0)      a -= fr;
            if (r == JW - 1) a -= br;
            float u = __builtin_fmaf(a, u1, -u0);
            unsigned s_ = __float_as_uint(u) >> 31;
            jc += (int)(s_ ^ sj);
            sj = s_;
            u0 = u1; u1 = u;
        }
        jct[c][p] = jc;
    }
    __syncthreads();

    if (c == 0) {
        int tot = xct[15][p];                   // seg 8 via its bwd chain
        #pragma unroll
        for (int cc = 0; cc < 8; ++cc) tot += xct[cc][p] + jct[cc][p];
        sc[p] = tot;
    }
    __syncthreads();

    // ---- (4) scatter eigenvalues (bracket-union, verified r3-r13) --------
    if (c == 0) {
        float* o = out + m * RN;
        const int ccur = sc[p];
        if (p > 0) {
            const int cprev = sc[p - 1];
            const float xm = x - 0.5f * step;
            for (int k = cprev; k < ccur; ++k) o[k] = xm;
        } else if (ch == 0) {
            const float xm = x - 0.5f * step;   // bracket (lo, x_0]
            for (int k = 0; k < ccur; ++k) o[k] = xm;
        }
        if (ch == NCHUNK - 1 && p == 15) {      // bracket (x_last, hi]
            const float xm = x + 0.5f * step;
            for (int k = ccur; k < RN; ++k) o[k] = xm;
        }
    }
}

// ---------------------------------------------------------------------------
extern "C" void kernel_launch(void* const* d_in, const int* in_sizes, int n_in,
                              void* d_out, int out_size, void* d_ws, size_t ws_size,
                              hipStream_t stream) {
    const float* ptl = (const float*)d_in[0];   // (B=4, RN) f32
    float* out = (float*)d_out;                 // (4, 4, RN) f32 ascending

    eval_eig_fused<<<NMAT * NCHUNK, 256, 0, stream>>>(ptl, out);
}